// Round 2
// baseline (568.579 us; speedup 1.0000x reference)
//
#include <hip/hip_runtime.h>
#include <stdint.h>

#define HID 256
#define RNUM 6
#define NNODE 40000
#define NEVENT 20000
#define NEDGE 200000
#define NKEY (NNODE*RNUM)      // 240000
#define KCAT 1792              // 6*256 + 256
#define EPSV 1e-5f

typedef unsigned short u16;
typedef unsigned int u32;
typedef __attribute__((ext_vector_type(4))) float f32x4;
typedef __attribute__((ext_vector_type(4))) unsigned short u16x4;
typedef __attribute__((ext_vector_type(8))) __bf16 bf16x8;

__device__ __forceinline__ float bf2f(u16 h) {
  union { u32 u; float f; } c; c.u = ((u32)h) << 16; return c.f;
}
__device__ __forceinline__ u16 f2bf(float f) {
  union { float f; u32 u; } c; c.f = f;
  return (u16)((c.u + 0x7fffu + ((c.u >> 16) & 1u)) >> 16);
}

// ---------------- small setup kernels ----------------

__global__ void zero_ints(int* p, int n) {
  int i = blockIdx.x * blockDim.x + threadIdx.x;
  if (i < n) p[i] = 0;
}

__global__ void count_keys(const int* __restrict__ dst, const int* __restrict__ typ,
                           int* __restrict__ cnt) {
  int e = blockIdx.x * blockDim.x + threadIdx.x;
  if (e >= NEDGE) return;
  atomicAdd(&cnt[dst[e] * RNUM + typ[e]], 1);
}

__global__ __launch_bounds__(256) void scan1(const int* __restrict__ cnt,
                                             int* __restrict__ offs,
                                             int* __restrict__ blockSums) {
  __shared__ int wsum[4];
  int t = threadIdx.x, b = blockIdx.x;
  int base = b * 1024 + t * 4;
  int v[4];
#pragma unroll
  for (int j = 0; j < 4; ++j) v[j] = (base + j < NKEY) ? cnt[base + j] : 0;
  int s = v[0] + v[1] + v[2] + v[3];
  int inc = s;
  int lane = t & 63, wv = t >> 6;
#pragma unroll
  for (int d = 1; d < 64; d <<= 1) {
    int o = __shfl_up(inc, d, 64);
    if (lane >= d) inc += o;
  }
  if (lane == 63) wsum[wv] = inc;
  __syncthreads();
  int wpre = 0;
  for (int w = 0; w < wv; ++w) wpre += wsum[w];
  int exc = wpre + inc - s;
  int run = exc;
#pragma unroll
  for (int j = 0; j < 4; ++j) {
    if (base + j < NKEY) offs[base + j] = run;
    run += v[j];
  }
  if (t == 255) blockSums[b] = wpre + inc;
}

__global__ void scan2(const int* __restrict__ blockSums, int* __restrict__ blockOff,
                      int nb, int* __restrict__ offs_last) {
  if (threadIdx.x == 0 && blockIdx.x == 0) {
    int run = 0;
    for (int i = 0; i < nb; ++i) { int c = blockSums[i]; blockOff[i] = run; run += c; }
    *offs_last = run;
  }
}

__global__ __launch_bounds__(256) void scan3(int* __restrict__ offs,
                                             const int* __restrict__ blockOff) {
  int t = threadIdx.x, b = blockIdx.x;
  int add = blockOff[b];
  int base = b * 1024 + t * 4;
#pragma unroll
  for (int j = 0; j < 4; ++j)
    if (base + j < NKEY) offs[base + j] += add;
}

__global__ void scatter_edges(const int* __restrict__ src, const int* __restrict__ dst,
                              const int* __restrict__ typ, const float* __restrict__ w,
                              const int* __restrict__ offs, int* __restrict__ tmpc,
                              int* __restrict__ sortedSrc, float* __restrict__ sortedW) {
  int e = blockIdx.x * blockDim.x + threadIdx.x;
  if (e >= NEDGE) return;
  int key = dst[e] * RNUM + typ[e];
  int pos = offs[key] + atomicAdd(&tmpc[key], 1);
  sortedSrc[pos] = src[e];
  sortedW[pos] = w[e];
}

// convert the 4 stacked fp32 inputs to one bf16 [40000][128]
__global__ void cvt_x(const float* __restrict__ xe, const float* __restrict__ xf,
                      const float* __restrict__ xp, const float* __restrict__ xi,
                      u16* __restrict__ xbf) {
  int i = blockIdx.x * blockDim.x + threadIdx.x;  // one per 4 elems
  if (i >= NNODE * 128 / 4) return;
  int e = i * 4;
  int row = e >> 7, col = e & 127;
  const float* srcp; int lr;
  if (row < 20000)      { srcp = xe; lr = row; }
  else if (row < 30000) { srcp = xf; lr = row - 20000; }
  else if (row < 38000) { srcp = xp; lr = row - 30000; }
  else                  { srcp = xi; lr = row - 38000; }
  f32x4 v = *(const f32x4*)&srcp[(size_t)lr * 128 + col];
  u16x4 o = { f2bf(v[0]), f2bf(v[1]), f2bf(v[2]), f2bf(v[3]) };
  *(u16x4*)&xbf[e] = o;
}

// projWt[t][n][k] = bf16(proj_W[t][k][n])
__global__ void build_projWt(const float* __restrict__ pw, u16* __restrict__ wt) {
  int i = blockIdx.x * blockDim.x + threadIdx.x;
  if (i >= 4 * 256 * 128) return;
  int t = i >> 15, rem = i & 32767, n = rem >> 7, k = rem & 127;
  wt[i] = f2bf(pw[((size_t)t * 128 + k) * 256 + n]);
}

// WcatT[l][o][k]: k<1536 -> sum_b comp[l][r][b]*basis[l][b][i][o]; else root[l][k-1536][o]
__global__ void build_wcat(const float* __restrict__ basis, const float* __restrict__ comp,
                           const float* __restrict__ root, u16* __restrict__ wcat) {
  int i = blockIdx.x * blockDim.x + threadIdx.x;
  if (i >= 3 * 256 * KCAT) return;
  int l = i / (256 * KCAT);
  int rem = i - l * 256 * KCAT;
  int o = rem / KCAT;
  int k = rem - o * KCAT;
  float s;
  if (k < 1536) {
    int r = k >> 8, ii = k & 255;
    s = 0.f;
#pragma unroll
    for (int b = 0; b < 8; ++b)
      s += comp[((size_t)l * 6 + r) * 8 + b] *
           basis[(((size_t)l * 8 + b) * 256 + ii) * 256 + o];
  } else {
    s = root[((size_t)l * 256 + (k - 1536)) * 256 + o];
  }
  wcat[i] = f2bf(s);
}

// Arel[r][c] = ete[r] @ emlp_W[:16, c] + emlp_b[c];  V[c] = emlp_W[16][c]
__global__ void build_arel(const float* __restrict__ ete, const float* __restrict__ emlpW,
                           const float* __restrict__ emlpb, float* __restrict__ Arel,
                           float* __restrict__ V) {
  int i = blockIdx.x * blockDim.x + threadIdx.x;
  if (i < 6 * 256) {
    int r = i >> 8, c = i & 255;
    float s = emlpb[c];
#pragma unroll
    for (int k = 0; k < 16; ++k) s += ete[r * 16 + k] * emlpW[k * 256 + c];
    Arel[i] = s;
  } else if (i < 6 * 256 + 256) {
    V[i - 6 * 256] = emlpW[16 * 256 + (i - 6 * 256)];
  }
}

// ---------------- GEMM: C[M,N] = A[M,K](bf16,row-major) x Bt[N,K](bf16) ----------------
// 128x128 tile, BK=32, 4 waves (2x2 of 64x64), global_load_lds staging (m97 structure)

__global__ __launch_bounds__(256) void gemm_bf16(const u16* __restrict__ A, int lda,
                                                 const u16* __restrict__ Bt, int ldb,
                                                 float* __restrict__ C, int ldc,
                                                 int M, int Kdim) {
  __shared__ __align__(16) u16 As[2][128 * 32];
  __shared__ __align__(16) u16 Bs[2][128 * 32];
  const int tid = threadIdx.x;
  const int v = tid >> 6, lane = tid & 63;
  const int m0 = blockIdx.x * 128;
  const int n0 = blockIdx.y * 128;
  const int wm = (v >> 1) * 64, wn = (v & 1) * 64;

  f32x4 acc[4][4];
#pragma unroll
  for (int i = 0; i < 4; ++i)
#pragma unroll
    for (int j = 0; j < 4; ++j) acc[i][j] = f32x4{0.f, 0.f, 0.f, 0.f};

  const int nk = Kdim >> 5;

  auto stage = [&](int kt, int buf) {
    const int k0 = kt << 5;
#pragma unroll
    for (int it = 0; it < 2; ++it) {
      int c = v * 64 + it * 256 + lane;
      int row = c >> 2, seg = c & 3;
      int ar = m0 + row; if (ar >= M) ar = M - 1;   // clamp (masked on store)
      const u16* ga = A + (size_t)ar * lda + k0 + seg * 8;
      __builtin_amdgcn_global_load_lds(
          (const __attribute__((address_space(1))) void*)ga,
          (__attribute__((address_space(3))) void*)(&As[buf][(v * 64 + it * 256) * 8]),
          16, 0, 0);
      int br = n0 + row;                             // always < N cols
      const u16* gb = Bt + (size_t)br * ldb + k0 + seg * 8;
      __builtin_amdgcn_global_load_lds(
          (const __attribute__((address_space(1))) void*)gb,
          (__attribute__((address_space(3))) void*)(&Bs[buf][(v * 64 + it * 256) * 8]),
          16, 0, 0);
    }
  };

  stage(0, 0);
  for (int kt = 0; kt < nk; ++kt) {
    __syncthreads();                       // stage(kt) complete, prior reads drained
    if (kt + 1 < nk) stage(kt + 1, (kt + 1) & 1);
    const u16* as = &As[kt & 1][0];
    const u16* bs = &Bs[kt & 1][0];
    bf16x8 af[4], bfr[4];
#pragma unroll
    for (int mi = 0; mi < 4; ++mi)
      af[mi] = *(const bf16x8*)&as[(wm + mi * 16 + (lane & 15)) * 32 + (lane >> 4) * 8];
#pragma unroll
    for (int ni = 0; ni < 4; ++ni)
      bfr[ni] = *(const bf16x8*)&bs[(wn + ni * 16 + (lane & 15)) * 32 + (lane >> 4) * 8];
#pragma unroll
    for (int mi = 0; mi < 4; ++mi)
#pragma unroll
      for (int ni = 0; ni < 4; ++ni)
        acc[mi][ni] = __builtin_amdgcn_mfma_f32_16x16x32_bf16(af[mi], bfr[ni],
                                                              acc[mi][ni], 0, 0, 0);
  }

  const int rr = (lane >> 4) * 4;
  const int cc = lane & 15;
#pragma unroll
  for (int mi = 0; mi < 4; ++mi) {
#pragma unroll
    for (int reg = 0; reg < 4; ++reg) {
      int row = m0 + wm + mi * 16 + rr + reg;
      if (row >= M) continue;
#pragma unroll
      for (int ni = 0; ni < 4; ++ni)
        C[(size_t)row * ldc + n0 + wn + ni * 16 + cc] = acc[mi][ni][reg];
    }
  }
}

// ---------------- per-row LN kernels (one wave per row) ----------------

__global__ __launch_bounds__(256) void proj_ln(const float* __restrict__ y,
                                               const float* __restrict__ pb,
                                               const float* __restrict__ pg,
                                               const float* __restrict__ pbeta,
                                               u16* __restrict__ h_bf) {
  int wid = (blockIdx.x * blockDim.x + threadIdx.x) >> 6;
  int lane = threadIdx.x & 63;
  if (wid >= NNODE) return;
  int t = wid < 20000 ? 0 : (wid < 30000 ? 1 : (wid < 38000 ? 2 : 3));
  size_t base = (size_t)wid * HID + lane * 4;
  int pbase = t * HID + lane * 4;
  f32x4 x = *(const f32x4*)&y[base];
  f32x4 bv0 = *(const f32x4*)&pb[pbase];
  x += bv0;
  float s = x[0] + x[1] + x[2] + x[3];
  float s2 = x[0] * x[0] + x[1] * x[1] + x[2] * x[2] + x[3] * x[3];
#pragma unroll
  for (int d = 1; d < 64; d <<= 1) { s += __shfl_xor(s, d, 64); s2 += __shfl_xor(s2, d, 64); }
  float mean = s * (1.f / HID);
  float var = s2 * (1.f / HID) - mean * mean;
  float rs = rsqrtf(var + EPSV);
  f32x4 gv = *(const f32x4*)&pg[pbase];
  f32x4 bv = *(const f32x4*)&pbeta[pbase];
  u16x4 hb;
#pragma unroll
  for (int j = 0; j < 4; ++j) {
    float tv = (x[j] - mean) * rs * gv[j] + bv[j];
    tv = tv > 0.f ? tv : 0.f;
    hb[j] = f2bf(tv);
  }
  *(u16x4*)&h_bf[base] = hb;
}

__global__ __launch_bounds__(256) void layer_epilogue(const float* __restrict__ y,
                                                      const u16* __restrict__ ebias,
                                                      const float* __restrict__ cb,
                                                      const float* __restrict__ g,
                                                      const float* __restrict__ b,
                                                      u16* __restrict__ h_bf,
                                                      float* __restrict__ outp) {
  int wid = (blockIdx.x * blockDim.x + threadIdx.x) >> 6;
  int lane = threadIdx.x & 63;
  if (wid >= NNODE) return;
  size_t base = (size_t)wid * HID + lane * 4;
  f32x4 x = *(const f32x4*)&y[base];
  u16x4 eb = *(const u16x4*)&ebias[base];
  f32x4 cbv = *(const f32x4*)&cb[lane * 4];
#pragma unroll
  for (int j = 0; j < 4; ++j) x[j] += bf2f(eb[j]) + cbv[j];
  float s = x[0] + x[1] + x[2] + x[3];
  float s2 = x[0] * x[0] + x[1] * x[1] + x[2] * x[2] + x[3] * x[3];
#pragma unroll
  for (int d = 1; d < 64; d <<= 1) { s += __shfl_xor(s, d, 64); s2 += __shfl_xor(s2, d, 64); }
  float mean = s * (1.f / HID);
  float var = s2 * (1.f / HID) - mean * mean;
  float rs = rsqrtf(var + EPSV);
  f32x4 gv = *(const f32x4*)&g[lane * 4];
  f32x4 bv = *(const f32x4*)&b[lane * 4];
  u16x4 hold = *(const u16x4*)&h_bf[base];
  u16x4 hb; f32x4 r;
#pragma unroll
  for (int j = 0; j < 4; ++j) {
    float tv = (x[j] - mean) * rs * gv[j] + bv[j];
    tv = tv > 0.f ? tv : 0.f;
    r[j] = tv + bf2f(hold[j]);
    hb[j] = f2bf(r[j]);
  }
  *(u16x4*)&h_bf[base] = hb;
  if (outp != nullptr && wid < NEVENT) *(f32x4*)&outp[base] = r;
}

// ---------------- edge_bias (once) and feat build (per layer) ----------------

__global__ __launch_bounds__(256) void build_edge_bias(const int* __restrict__ offs,
                                                       const float* __restrict__ sortedW,
                                                       const float* __restrict__ Arel,
                                                       const float* __restrict__ V,
                                                       u16* __restrict__ ebias) {
  int n = (blockIdx.x * blockDim.x + threadIdx.x) >> 6;
  int lane = threadIdx.x & 63;
  if (n >= NNODE) return;
  f32x4 vv = *(const f32x4*)&V[lane * 4];
  f32x4 acc = {0.f, 0.f, 0.f, 0.f};
  int beg0 = offs[n * RNUM];
#pragma unroll
  for (int r = 0; r < RNUM; ++r) {
    int b0 = offs[n * RNUM + r], b1 = offs[n * RNUM + r + 1];
    if (b0 == b1) continue;
    f32x4 av = *(const f32x4*)&Arel[r * HID + lane * 4];
    for (int p = b0; p < b1; ++p) {
      float wv = sortedW[p];
#pragma unroll
      for (int j = 0; j < 4; ++j) {
        float t = av[j] + wv * vv[j];
        acc[j] += t > 0.f ? t : 0.f;
      }
    }
  }
  int deg = offs[n * RNUM + RNUM] - beg0;
  float sc = 0.1f / (float)(deg > 1 ? deg : 1);
  u16x4 o = { f2bf(acc[0] * sc), f2bf(acc[1] * sc), f2bf(acc[2] * sc), f2bf(acc[3] * sc) };
  *(u16x4*)&ebias[(size_t)n * HID + lane * 4] = o;
}

// one wave per (dst,rel) segment: mean of gathered h rows -> feat[:, r*256:...]
// plus NNODE extra waves copying h into feat[:, 1536:1792]
__global__ __launch_bounds__(256) void build_feat(const u16* __restrict__ h_bf,
                                                  const int* __restrict__ offs,
                                                  const int* __restrict__ sortedSrc,
                                                  u16* __restrict__ feat) {
  int wid = (blockIdx.x * blockDim.x + threadIdx.x) >> 6;
  int lane = threadIdx.x & 63;
  if (wid < NKEY) {
    int beg = offs[wid], end = offs[wid + 1];
    float a0 = 0.f, a1 = 0.f, a2 = 0.f, a3 = 0.f;
    for (int p = beg; p < end; ++p) {
      int sidx = sortedSrc[p];
      u16x4 hv = *(const u16x4*)&h_bf[(size_t)sidx * HID + lane * 4];
      a0 += bf2f(hv[0]); a1 += bf2f(hv[1]); a2 += bf2f(hv[2]); a3 += bf2f(hv[3]);
    }
    int c = end - beg;
    float inv = c > 0 ? 1.f / (float)c : 1.f;
    int n = wid / RNUM, r = wid - n * RNUM;
    u16x4 o = { f2bf(a0 * inv), f2bf(a1 * inv), f2bf(a2 * inv), f2bf(a3 * inv) };
    *(u16x4*)&feat[(size_t)n * KCAT + r * HID + lane * 4] = o;
  } else if (wid < NKEY + NNODE) {
    int n = wid - NKEY;
    u16x4 hv = *(const u16x4*)&h_bf[(size_t)n * HID + lane * 4];
    *(u16x4*)&feat[(size_t)n * KCAT + 1536 + lane * 4] = hv;
  }
}

// ---------------- launch ----------------

extern "C" void kernel_launch(void* const* d_in, const int* in_sizes, int n_in,
                              void* d_out, int out_size, void* d_ws, size_t ws_size,
                              hipStream_t stream) {
  const float* x_event = (const float*)d_in[0];
  const float* x_file  = (const float*)d_in[1];
  const float* x_proc  = (const float*)d_in[2];
  const float* x_ip    = (const float*)d_in[3];
  const int*   e_src   = (const int*)d_in[4];
  const int*   e_dst   = (const int*)d_in[5];
  const int*   e_typ   = (const int*)d_in[6];
  const float* e_w     = (const float*)d_in[7];
  const float* proj_W  = (const float*)d_in[8];
  const float* proj_b  = (const float*)d_in[9];
  const float* proj_g  = (const float*)d_in[10];
  const float* proj_be = (const float*)d_in[11];
  const float* ete     = (const float*)d_in[12];
  const float* emlpW   = (const float*)d_in[13];
  const float* emlpb   = (const float*)d_in[14];
  const float* basis   = (const float*)d_in[15];
  const float* comp    = (const float*)d_in[16];
  const float* root    = (const float*)d_in[17];
  const float* convb   = (const float*)d_in[18];
  const float* ln_g    = (const float*)d_in[19];
  const float* ln_b    = (const float*)d_in[20];
  float* outp = (float*)d_out;

  char* p = (char*)d_ws;
  auto alloc = [&](size_t bytes) {
    char* r = p; p += (bytes + 255) & ~(size_t)255; return r;
  };
  // total ws usage: ~222 MiB
  u16*   feat    = (u16*)  alloc((size_t)NNODE * KCAT * 2);   // 143.4 MB
  u16*   h_bf    = (u16*)  alloc((size_t)NNODE * HID * 2);    // 20.5 MB
  float* y       = (float*)alloc((size_t)NNODE * HID * 4);    // 41.0 MB
  u16*   ebias   = (u16*)  alloc((size_t)NNODE * HID * 2);    // 20.5 MB
  u16*   projWt  = (u16*)  alloc((size_t)4 * HID * 128 * 2);
  u16*   WcatT   = (u16*)  alloc((size_t)3 * HID * KCAT * 2);
  float* Arel    = (float*)alloc(6 * HID * 4);
  float* Vv      = (float*)alloc(HID * 4);
  int*   cnt     = (int*)  alloc(NKEY * 4);
  int*   tmpc    = (int*)  alloc(NKEY * 4);
  int*   offs    = (int*)  alloc((NKEY + 1) * 4);
  int*   bSums   = (int*)  alloc(256 * 4);
  int*   bOff    = (int*)  alloc(256 * 4);
  int*   sSrc    = (int*)  alloc((size_t)NEDGE * 4);
  float* sW      = (float*)alloc((size_t)NEDGE * 4);
  u16*   xbf     = feat;   // alias: xbf dead before feat is first written
  (void)in_sizes; (void)n_in; (void)out_size; (void)ws_size;

  const int NB1 = (NKEY + 1023) / 1024;  // 235

  zero_ints<<<(NKEY + 255) / 256, 256, 0, stream>>>(cnt, NKEY);
  zero_ints<<<(NKEY + 255) / 256, 256, 0, stream>>>(tmpc, NKEY);
  count_keys<<<(NEDGE + 255) / 256, 256, 0, stream>>>(e_dst, e_typ, cnt);
  scan1<<<NB1, 256, 0, stream>>>(cnt, offs, bSums);
  scan2<<<1, 1, 0, stream>>>(bSums, bOff, NB1, offs + NKEY);
  scan3<<<NB1, 256, 0, stream>>>(offs, bOff);
  scatter_edges<<<(NEDGE + 255) / 256, 256, 0, stream>>>(e_src, e_dst, e_typ, e_w,
                                                         offs, tmpc, sSrc, sW);

  cvt_x<<<(NNODE * 32 + 255) / 256, 256, 0, stream>>>(x_event, x_file, x_proc, x_ip, xbf);
  build_projWt<<<(4 * 256 * 128 + 255) / 256, 256, 0, stream>>>(proj_W, projWt);
  build_wcat<<<(3 * 256 * KCAT + 255) / 256, 256, 0, stream>>>(basis, comp, root, WcatT);
  build_arel<<<8, 256, 0, stream>>>(ete, emlpW, emlpb, Arel, Vv);

  // per-type input projection GEMMs
  {
    int offr[5] = {0, 20000, 30000, 38000, 40000};
    for (int t = 0; t < 4; ++t) {
      int M = offr[t + 1] - offr[t];
      dim3 g((M + 127) / 128, 2);
      gemm_bf16<<<g, 256, 0, stream>>>(xbf + (size_t)offr[t] * 128, 128,
                                       projWt + (size_t)t * HID * 128, 128,
                                       y + (size_t)offr[t] * HID, HID, M, 128);
    }
  }
  proj_ln<<<(NNODE * 64 + 255) / 256, 256, 0, stream>>>(y, proj_b, proj_g, proj_be, h_bf);
  build_edge_bias<<<(NNODE * 64 + 255) / 256, 256, 0, stream>>>(offs, sW, Arel, Vv, ebias);

  for (int l = 0; l < 3; ++l) {
    build_feat<<<((NKEY + NNODE) * 64) / 256, 256, 0, stream>>>(h_bf, offs, sSrc, feat);
    dim3 g((NNODE + 127) / 128, 2);
    gemm_bf16<<<g, 256, 0, stream>>>(feat, KCAT,
                                     WcatT + (size_t)l * HID * KCAT, KCAT,
                                     y, HID, NNODE, KCAT);
    layer_epilogue<<<(NNODE * 64 + 255) / 256, 256, 0, stream>>>(
        y, ebias, convb + l * HID, ln_g + l * HID, ln_b + l * HID,
        h_bf, (l == 2) ? outp : nullptr);
  }
}

// Round 3
// 486.265 us; speedup vs baseline: 1.1693x; 1.1693x over previous
//
#include <hip/hip_runtime.h>
#include <stdint.h>

#define HID 256
#define RNUM 6
#define NNODE 40000
#define NEVENT 20000
#define NEDGE 200000
#define NKEY (NNODE*RNUM)      // 240000
#define KCAT 1792              // 6*256 + 256 (z row width / Wall N-dim)
#define EPSV 1e-5f

typedef unsigned short u16;
typedef unsigned int u32;
typedef __attribute__((ext_vector_type(4))) float f32x4;
typedef __attribute__((ext_vector_type(4))) unsigned short u16x4;
typedef __attribute__((ext_vector_type(8))) __bf16 bf16x8;

__device__ __forceinline__ float bf2f(u16 h) {
  union { u32 u; float f; } c; c.u = ((u32)h) << 16; return c.f;
}
__device__ __forceinline__ u16 f2bf(float f) {
  union { float f; u32 u; } c; c.f = f;
  return (u16)((c.u + 0x7fffu + ((c.u >> 16) & 1u)) >> 16);
}

// ---------------- small setup kernels ----------------

__global__ void zero_ints(int* p, int n) {
  int i = blockIdx.x * blockDim.x + threadIdx.x;
  if (i < n) p[i] = 0;
}

__global__ void count_keys(const int* __restrict__ dst, const int* __restrict__ typ,
                           int* __restrict__ cnt) {
  int e = blockIdx.x * blockDim.x + threadIdx.x;
  if (e >= NEDGE) return;
  atomicAdd(&cnt[dst[e] * RNUM + typ[e]], 1);
}

__global__ __launch_bounds__(256) void scan1(const int* __restrict__ cnt,
                                             int* __restrict__ offs,
                                             int* __restrict__ blockSums) {
  __shared__ int wsum[4];
  int t = threadIdx.x, b = blockIdx.x;
  int base = b * 1024 + t * 4;
  int v[4];
#pragma unroll
  for (int j = 0; j < 4; ++j) v[j] = (base + j < NKEY) ? cnt[base + j] : 0;
  int s = v[0] + v[1] + v[2] + v[3];
  int inc = s;
  int lane = t & 63, wv = t >> 6;
#pragma unroll
  for (int d = 1; d < 64; d <<= 1) {
    int o = __shfl_up(inc, d, 64);
    if (lane >= d) inc += o;
  }
  if (lane == 63) wsum[wv] = inc;
  __syncthreads();
  int wpre = 0;
  for (int w = 0; w < wv; ++w) wpre += wsum[w];
  int exc = wpre + inc - s;
  int run = exc;
#pragma unroll
  for (int j = 0; j < 4; ++j) {
    if (base + j < NKEY) offs[base + j] = run;
    run += v[j];
  }
  if (t == 255) blockSums[b] = wpre + inc;
}

__global__ void scan2(const int* __restrict__ blockSums, int* __restrict__ blockOff,
                      int nb, int* __restrict__ offs_last) {
  if (threadIdx.x == 0 && blockIdx.x == 0) {
    int run = 0;
    for (int i = 0; i < nb; ++i) { int c = blockSums[i]; blockOff[i] = run; run += c; }
    *offs_last = run;
  }
}

__global__ __launch_bounds__(256) void scan3(int* __restrict__ offs,
                                             const int* __restrict__ blockOff) {
  int t = threadIdx.x, b = blockIdx.x;
  int add = blockOff[b];
  int base = b * 1024 + t * 4;
#pragma unroll
  for (int j = 0; j < 4; ++j)
    if (base + j < NKEY) offs[base + j] += add;
}

__global__ void scatter_edges(const int* __restrict__ src, const int* __restrict__ dst,
                              const int* __restrict__ typ, const float* __restrict__ w,
                              const int* __restrict__ offs, int* __restrict__ tmpc,
                              int* __restrict__ sortedSrc, float* __restrict__ sortedW) {
  int e = blockIdx.x * blockDim.x + threadIdx.x;
  if (e >= NEDGE) return;
  int key = dst[e] * RNUM + typ[e];
  int pos = offs[key] + atomicAdd(&tmpc[key], 1);
  sortedSrc[pos] = src[e];
  sortedW[pos] = w[e];
}

// convert the 4 stacked fp32 inputs to one bf16 [40000][128]
__global__ void cvt_x(const float* __restrict__ xe, const float* __restrict__ xf,
                      const float* __restrict__ xp, const float* __restrict__ xi,
                      u16* __restrict__ xbf) {
  int i = blockIdx.x * blockDim.x + threadIdx.x;  // one per 4 elems
  if (i >= NNODE * 128 / 4) return;
  int e = i * 4;
  int row = e >> 7, col = e & 127;
  const float* srcp; int lr;
  if (row < 20000)      { srcp = xe; lr = row; }
  else if (row < 30000) { srcp = xf; lr = row - 20000; }
  else if (row < 38000) { srcp = xp; lr = row - 30000; }
  else                  { srcp = xi; lr = row - 38000; }
  f32x4 v = *(const f32x4*)&srcp[(size_t)lr * 128 + col];
  u16x4 o = { f2bf(v[0]), f2bf(v[1]), f2bf(v[2]), f2bf(v[3]) };
  *(u16x4*)&xbf[e] = o;
}

// projWt[t][n][k] = bf16(proj_W[t][k][n])
__global__ void build_projWt(const float* __restrict__ pw, u16* __restrict__ wt) {
  int i = blockIdx.x * blockDim.x + threadIdx.x;
  if (i >= 4 * 256 * 128) return;
  int t = i >> 15, rem = i & 32767, n = rem >> 7, k = rem & 127;
  wt[i] = f2bf(pw[((size_t)t * 128 + k) * 256 + n]);
}

// WallT[l][og][k]: og<1536 -> W_r[k][o] = sum_b comp[l][r][b]*basis[l][b][k][o]
//                  og>=1536 -> root[l][k][og-1536]
__global__ void build_wall(const float* __restrict__ basis, const float* __restrict__ comp,
                           const float* __restrict__ root, u16* __restrict__ wall) {
  int i = blockIdx.x * blockDim.x + threadIdx.x;
  if (i >= 3 * KCAT * 256) return;
  int l = i / (KCAT * 256);
  int rem = i - l * KCAT * 256;
  int og = rem >> 8;
  int k = rem & 255;
  float s;
  if (og < 1536) {
    int r = og >> 8, o = og & 255;
    s = 0.f;
#pragma unroll
    for (int b = 0; b < 8; ++b)
      s += comp[((size_t)l * 6 + r) * 8 + b] *
           basis[(((size_t)l * 8 + b) * 256 + k) * 256 + o];
  } else {
    s = root[((size_t)l * 256 + k) * 256 + (og - 1536)];
  }
  wall[i] = f2bf(s);
}

// Arel[r][c] = ete[r] @ emlp_W[:16, c] + emlp_b[c];  V[c] = emlp_W[16][c]
__global__ void build_arel(const float* __restrict__ ete, const float* __restrict__ emlpW,
                           const float* __restrict__ emlpb, float* __restrict__ Arel,
                           float* __restrict__ V) {
  int i = blockIdx.x * blockDim.x + threadIdx.x;
  if (i < 6 * 256) {
    int r = i >> 8, c = i & 255;
    float s = emlpb[c];
#pragma unroll
    for (int k = 0; k < 16; ++k) s += ete[r * 16 + k] * emlpW[k * 256 + c];
    Arel[i] = s;
  } else if (i < 6 * 256 + 256) {
    V[i - 6 * 256] = emlpW[16 * 256 + (i - 6 * 256)];
  }
}

// ---------------- GEMM: C[M,N] = A[M,K](bf16,row-major) x Bt[N,K](bf16) ----------------
// 128x128 tile, BK=32, 4 waves (2x2 of 64x64), global_load_lds staging (m97 structure)
// grid: (N/128, ceil(M/128)) — consecutive blocks share the A panel (L2 reuse)

template <bool BF16_OUT>
__global__ __launch_bounds__(256) void gemm_bf16(const u16* __restrict__ A, int lda,
                                                 const u16* __restrict__ Bt, int ldb,
                                                 void* __restrict__ Cv, int ldc,
                                                 int M, int Kdim) {
  __shared__ __align__(16) u16 As[2][128 * 32];
  __shared__ __align__(16) u16 Bs[2][128 * 32];
  const int tid = threadIdx.x;
  const int v = tid >> 6, lane = tid & 63;
  const int n0 = blockIdx.x * 128;
  const int m0 = blockIdx.y * 128;
  const int wm = (v >> 1) * 64, wn = (v & 1) * 64;

  f32x4 acc[4][4];
#pragma unroll
  for (int i = 0; i < 4; ++i)
#pragma unroll
    for (int j = 0; j < 4; ++j) acc[i][j] = f32x4{0.f, 0.f, 0.f, 0.f};

  const int nk = Kdim >> 5;

  auto stage = [&](int kt, int buf) {
    const int k0 = kt << 5;
#pragma unroll
    for (int it = 0; it < 2; ++it) {
      int c = v * 64 + it * 256 + lane;
      int row = c >> 2, seg = c & 3;
      int ar = m0 + row; if (ar >= M) ar = M - 1;   // clamp (masked on store)
      const u16* ga = A + (size_t)ar * lda + k0 + seg * 8;
      __builtin_amdgcn_global_load_lds(
          (const __attribute__((address_space(1))) void*)ga,
          (__attribute__((address_space(3))) void*)(&As[buf][(v * 64 + it * 256) * 8]),
          16, 0, 0);
      int br = n0 + row;                             // always < N cols
      const u16* gb = Bt + (size_t)br * ldb + k0 + seg * 8;
      __builtin_amdgcn_global_load_lds(
          (const __attribute__((address_space(1))) void*)gb,
          (__attribute__((address_space(3))) void*)(&Bs[buf][(v * 64 + it * 256) * 8]),
          16, 0, 0);
    }
  };

  stage(0, 0);
  for (int kt = 0; kt < nk; ++kt) {
    __syncthreads();                       // stage(kt) complete, prior reads drained
    if (kt + 1 < nk) stage(kt + 1, (kt + 1) & 1);
    const u16* as = &As[kt & 1][0];
    const u16* bs = &Bs[kt & 1][0];
    bf16x8 af[4], bfr[4];
#pragma unroll
    for (int mi = 0; mi < 4; ++mi)
      af[mi] = *(const bf16x8*)&as[(wm + mi * 16 + (lane & 15)) * 32 + (lane >> 4) * 8];
#pragma unroll
    for (int ni = 0; ni < 4; ++ni)
      bfr[ni] = *(const bf16x8*)&bs[(wn + ni * 16 + (lane & 15)) * 32 + (lane >> 4) * 8];
#pragma unroll
    for (int mi = 0; mi < 4; ++mi)
#pragma unroll
      for (int ni = 0; ni < 4; ++ni)
        acc[mi][ni] = __builtin_amdgcn_mfma_f32_16x16x32_bf16(af[mi], bfr[ni],
                                                              acc[mi][ni], 0, 0, 0);
  }

  const int rr = (lane >> 4) * 4;
  const int cc = lane & 15;
#pragma unroll
  for (int mi = 0; mi < 4; ++mi) {
#pragma unroll
    for (int reg = 0; reg < 4; ++reg) {
      int row = m0 + wm + mi * 16 + rr + reg;
      if (row >= M) continue;
#pragma unroll
      for (int ni = 0; ni < 4; ++ni) {
        if constexpr (BF16_OUT) {
          ((u16*)Cv)[(size_t)row * ldc + n0 + wn + ni * 16 + cc] = f2bf(acc[mi][ni][reg]);
        } else {
          ((float*)Cv)[(size_t)row * ldc + n0 + wn + ni * 16 + cc] = acc[mi][ni][reg];
        }
      }
    }
  }
}

// ---------------- per-row LN (proj phase) ----------------

__global__ __launch_bounds__(256) void proj_ln(const float* __restrict__ y,
                                               const float* __restrict__ pb,
                                               const float* __restrict__ pg,
                                               const float* __restrict__ pbeta,
                                               u16* __restrict__ h_bf) {
  int wid = (blockIdx.x * blockDim.x + threadIdx.x) >> 6;
  int lane = threadIdx.x & 63;
  if (wid >= NNODE) return;
  int t = wid < 20000 ? 0 : (wid < 30000 ? 1 : (wid < 38000 ? 2 : 3));
  size_t base = (size_t)wid * HID + lane * 4;
  int pbase = t * HID + lane * 4;
  f32x4 x = *(const f32x4*)&y[base];
  f32x4 bv0 = *(const f32x4*)&pb[pbase];
  x += bv0;
  float s = x[0] + x[1] + x[2] + x[3];
  float s2 = x[0] * x[0] + x[1] * x[1] + x[2] * x[2] + x[3] * x[3];
#pragma unroll
  for (int d = 1; d < 64; d <<= 1) { s += __shfl_xor(s, d, 64); s2 += __shfl_xor(s2, d, 64); }
  float mean = s * (1.f / HID);
  float var = s2 * (1.f / HID) - mean * mean;
  float rs = rsqrtf(var + EPSV);
  f32x4 gv = *(const f32x4*)&pg[pbase];
  f32x4 bv = *(const f32x4*)&pbeta[pbase];
  u16x4 hb;
#pragma unroll
  for (int j = 0; j < 4; ++j) {
    float tv = (x[j] - mean) * rs * gv[j] + bv[j];
    tv = tv > 0.f ? tv : 0.f;
    hb[j] = f2bf(tv);
  }
  *(u16x4*)&h_bf[base] = hb;
}

// ---------------- edge_bias (once) ----------------

__global__ __launch_bounds__(256) void build_edge_bias(const int* __restrict__ offs,
                                                       const float* __restrict__ sortedW,
                                                       const float* __restrict__ Arel,
                                                       const float* __restrict__ V,
                                                       u16* __restrict__ ebias) {
  int n = (blockIdx.x * blockDim.x + threadIdx.x) >> 6;
  int lane = threadIdx.x & 63;
  if (n >= NNODE) return;
  f32x4 vv = *(const f32x4*)&V[lane * 4];
  f32x4 acc = {0.f, 0.f, 0.f, 0.f};
  int beg0 = offs[n * RNUM];
#pragma unroll
  for (int r = 0; r < RNUM; ++r) {
    int b0 = offs[n * RNUM + r], b1 = offs[n * RNUM + r + 1];
    if (b0 == b1) continue;
    f32x4 av = *(const f32x4*)&Arel[r * HID + lane * 4];
    for (int p = b0; p < b1; ++p) {
      float wv = sortedW[p];
#pragma unroll
      for (int j = 0; j < 4; ++j) {
        float t = av[j] + wv * vv[j];
        acc[j] += t > 0.f ? t : 0.f;
      }
    }
  }
  int deg = offs[n * RNUM + RNUM] - beg0;
  float sc = 0.1f / (float)(deg > 1 ? deg : 1);
  u16x4 o = { f2bf(acc[0] * sc), f2bf(acc[1] * sc), f2bf(acc[2] * sc), f2bf(acc[3] * sc) };
  *(u16x4*)&ebias[(size_t)n * HID + lane * 4] = o;
}

// ---------------- fused aggregation + epilogue (per layer) ----------------
// one wave per node: h_new[n] = sum_r mean_{e in (n,r)} z[src_e, r*256:] + z[n,1536:]
//                  + conv_bias + edge_bias; LN; relu; h = h_new + h

__global__ __launch_bounds__(256) void agg_epilogue(const u16* __restrict__ z,
                                                    const int* __restrict__ offs,
                                                    const int* __restrict__ sortedSrc,
                                                    const u16* __restrict__ ebias,
                                                    const float* __restrict__ cb,
                                                    const float* __restrict__ g,
                                                    const float* __restrict__ b,
                                                    u16* __restrict__ h_bf,
                                                    float* __restrict__ outp) {
  int n = (blockIdx.x * blockDim.x + threadIdx.x) >> 6;
  int lane = threadIdx.x & 63;
  if (n >= NNODE) return;
  int col = lane * 4;
  f32x4 x = {0.f, 0.f, 0.f, 0.f};
#pragma unroll
  for (int r = 0; r < RNUM; ++r) {
    int b0 = offs[n * RNUM + r], b1 = offs[n * RNUM + r + 1];
    if (b0 == b1) continue;
    f32x4 s = {0.f, 0.f, 0.f, 0.f};
    for (int pp = b0; pp < b1; ++pp) {
      int src = sortedSrc[pp];
      u16x4 zv = *(const u16x4*)&z[(size_t)src * KCAT + r * HID + col];
      s[0] += bf2f(zv[0]); s[1] += bf2f(zv[1]); s[2] += bf2f(zv[2]); s[3] += bf2f(zv[3]);
    }
    float inv = 1.f / (float)(b1 - b0);
#pragma unroll
    for (int j = 0; j < 4; ++j) x[j] += s[j] * inv;
  }
  // root part + conv bias + edge bias
  u16x4 zr = *(const u16x4*)&z[(size_t)n * KCAT + 1536 + col];
  u16x4 eb = *(const u16x4*)&ebias[(size_t)n * HID + col];
  f32x4 cbv = *(const f32x4*)&cb[col];
#pragma unroll
  for (int j = 0; j < 4; ++j) x[j] += bf2f(zr[j]) + cbv[j] + bf2f(eb[j]);
  // LayerNorm stats over 256 elems
  float s = x[0] + x[1] + x[2] + x[3];
  float s2 = x[0] * x[0] + x[1] * x[1] + x[2] * x[2] + x[3] * x[3];
#pragma unroll
  for (int d = 1; d < 64; d <<= 1) { s += __shfl_xor(s, d, 64); s2 += __shfl_xor(s2, d, 64); }
  float mean = s * (1.f / HID);
  float var = s2 * (1.f / HID) - mean * mean;
  float rs = rsqrtf(var + EPSV);
  f32x4 gv = *(const f32x4*)&g[col];
  f32x4 bv = *(const f32x4*)&b[col];
  size_t base = (size_t)n * HID + col;
  u16x4 hold = *(const u16x4*)&h_bf[base];
  u16x4 hb; f32x4 r;
#pragma unroll
  for (int j = 0; j < 4; ++j) {
    float tv = (x[j] - mean) * rs * gv[j] + bv[j];
    tv = tv > 0.f ? tv : 0.f;
    r[j] = tv + bf2f(hold[j]);
    hb[j] = f2bf(r[j]);
  }
  *(u16x4*)&h_bf[base] = hb;
  if (outp != nullptr && n < NEVENT) *(f32x4*)&outp[base] = r;
}

// ---------------- launch ----------------

extern "C" void kernel_launch(void* const* d_in, const int* in_sizes, int n_in,
                              void* d_out, int out_size, void* d_ws, size_t ws_size,
                              hipStream_t stream) {
  const float* x_event = (const float*)d_in[0];
  const float* x_file  = (const float*)d_in[1];
  const float* x_proc  = (const float*)d_in[2];
  const float* x_ip    = (const float*)d_in[3];
  const int*   e_src   = (const int*)d_in[4];
  const int*   e_dst   = (const int*)d_in[5];
  const int*   e_typ   = (const int*)d_in[6];
  const float* e_w     = (const float*)d_in[7];
  const float* proj_W  = (const float*)d_in[8];
  const float* proj_b  = (const float*)d_in[9];
  const float* proj_g  = (const float*)d_in[10];
  const float* proj_be = (const float*)d_in[11];
  const float* ete     = (const float*)d_in[12];
  const float* emlpW   = (const float*)d_in[13];
  const float* emlpb   = (const float*)d_in[14];
  const float* basis   = (const float*)d_in[15];
  const float* comp    = (const float*)d_in[16];
  const float* root    = (const float*)d_in[17];
  const float* convb   = (const float*)d_in[18];
  const float* ln_g    = (const float*)d_in[19];
  const float* ln_b    = (const float*)d_in[20];
  float* outp = (float*)d_out;

  char* p = (char*)d_ws;
  auto alloc = [&](size_t bytes) {
    char* r = p; p += (bytes + 255) & ~(size_t)255; return r;
  };
  // total ws usage: ~203 MiB
  u16*   z       = (u16*)  alloc((size_t)NNODE * KCAT * 2);   // 143.4 MB
  u16*   h_bf    = (u16*)  alloc((size_t)NNODE * HID * 2);    // 20.5 MB
  u16*   ebias   = (u16*)  alloc((size_t)NNODE * HID * 2);    // 20.5 MB
  u16*   xbf     = (u16*)  alloc((size_t)NNODE * 128 * 2);    // 10.3 MB
  u16*   projWt  = (u16*)  alloc((size_t)4 * HID * 128 * 2);
  u16*   WallT   = (u16*)  alloc((size_t)3 * KCAT * 256 * 2); // 2.75 MB
  float* Arel    = (float*)alloc(6 * HID * 4);
  float* Vv      = (float*)alloc(HID * 4);
  int*   cnt     = (int*)  alloc(NKEY * 4);
  int*   tmpc    = (int*)  alloc(NKEY * 4);
  int*   offs    = (int*)  alloc((NKEY + 1) * 4);
  int*   bSums   = (int*)  alloc(256 * 4);
  int*   bOff    = (int*)  alloc(256 * 4);
  int*   sSrc    = (int*)  alloc((size_t)NEDGE * 4);
  float* sW      = (float*)alloc((size_t)NEDGE * 4);
  float* y       = (float*)z;   // alias: y (proj output, 41 MB fp32) dead before z written
  (void)in_sizes; (void)n_in; (void)out_size; (void)ws_size;

  const int NB1 = (NKEY + 1023) / 1024;  // 235

  zero_ints<<<(NKEY + 255) / 256, 256, 0, stream>>>(cnt, NKEY);
  zero_ints<<<(NKEY + 255) / 256, 256, 0, stream>>>(tmpc, NKEY);
  count_keys<<<(NEDGE + 255) / 256, 256, 0, stream>>>(e_dst, e_typ, cnt);
  scan1<<<NB1, 256, 0, stream>>>(cnt, offs, bSums);
  scan2<<<1, 1, 0, stream>>>(bSums, bOff, NB1, offs + NKEY);
  scan3<<<NB1, 256, 0, stream>>>(offs, bOff);
  scatter_edges<<<(NEDGE + 255) / 256, 256, 0, stream>>>(e_src, e_dst, e_typ, e_w,
                                                         offs, tmpc, sSrc, sW);

  cvt_x<<<(NNODE * 32 + 255) / 256, 256, 0, stream>>>(x_event, x_file, x_proc, x_ip, xbf);
  build_projWt<<<(4 * 256 * 128 + 255) / 256, 256, 0, stream>>>(proj_W, projWt);
  build_wall<<<(3 * KCAT * 256 + 255) / 256, 256, 0, stream>>>(basis, comp, root, WallT);
  build_arel<<<8, 256, 0, stream>>>(ete, emlpW, emlpb, Arel, Vv);

  // per-type input projection GEMMs (write fp32 y = z alias)
  {
    int offr[5] = {0, 20000, 30000, 38000, 40000};
    for (int t = 0; t < 4; ++t) {
      int M = offr[t + 1] - offr[t];
      dim3 g(2, (M + 127) / 128);
      gemm_bf16<false><<<g, 256, 0, stream>>>(xbf + (size_t)offr[t] * 128, 128,
                                              projWt + (size_t)t * HID * 128, 128,
                                              y + (size_t)offr[t] * HID, HID, M, 128);
    }
  }
  proj_ln<<<(NNODE * 64 + 255) / 256, 256, 0, stream>>>(y, proj_b, proj_g, proj_be, h_bf);
  build_edge_bias<<<(NNODE * 64 + 255) / 256, 256, 0, stream>>>(offs, sW, Arel, Vv, ebias);

  for (int l = 0; l < 3; ++l) {
    // z[40000, 1792] = h_bf[40000, 256] @ WallT_l^T   (bf16 out)
    dim3 g(KCAT / 128, (NNODE + 127) / 128);   // (14, 313)
    gemm_bf16<true><<<g, 256, 0, stream>>>(h_bf, HID,
                                           WallT + (size_t)l * KCAT * 256, 256,
                                           z, KCAT, NNODE, 256);
    agg_epilogue<<<(NNODE * 64 + 255) / 256, 256, 0, stream>>>(
        z, offs, sSrc, ebias, convb + l * HID, ln_g + l * HID, ln_b + l * HID,
        h_bf, (l == 2) ? outp : nullptr);
  }
}

// Round 4
// 445.139 us; speedup vs baseline: 1.2773x; 1.0924x over previous
//
#include <hip/hip_runtime.h>
#include <stdint.h>

#define HID 256
#define RNUM 6
#define NNODE 40000
#define NEVENT 20000
#define NEDGE 200000
#define NKEY (NNODE*RNUM)      // 240000
#define KCAT 1792              // 6*256 + 256 (z row width / Wall N-dim)
#define EPSV 1e-5f

typedef unsigned short u16;
typedef unsigned int u32;
typedef __attribute__((ext_vector_type(4))) float f32x4;
typedef __attribute__((ext_vector_type(4))) unsigned short u16x4;
typedef __attribute__((ext_vector_type(8))) __bf16 bf16x8;

__device__ __forceinline__ float bf2f(u16 h) {
  union { u32 u; float f; } c; c.u = ((u32)h) << 16; return c.f;
}
__device__ __forceinline__ u16 f2bf(float f) {
  union { float f; u32 u; } c; c.f = f;
  return (u16)((c.u + 0x7fffu + ((c.u >> 16) & 1u)) >> 16);
}

// ---------------- small setup kernels ----------------

__global__ void zero_ints(int* p, int n) {
  int i = blockIdx.x * blockDim.x + threadIdx.x;
  if (i < n) p[i] = 0;
}

__global__ void count_keys(const int* __restrict__ dst, const int* __restrict__ typ,
                           int* __restrict__ cnt) {
  int e = blockIdx.x * blockDim.x + threadIdx.x;
  if (e >= NEDGE) return;
  atomicAdd(&cnt[dst[e] * RNUM + typ[e]], 1);
}

__global__ __launch_bounds__(256) void scan1(const int* __restrict__ cnt,
                                             int* __restrict__ offs,
                                             int* __restrict__ blockSums) {
  __shared__ int wsum[4];
  int t = threadIdx.x, b = blockIdx.x;
  int base = b * 1024 + t * 4;
  int v[4];
#pragma unroll
  for (int j = 0; j < 4; ++j) v[j] = (base + j < NKEY) ? cnt[base + j] : 0;
  int s = v[0] + v[1] + v[2] + v[3];
  int inc = s;
  int lane = t & 63, wv = t >> 6;
#pragma unroll
  for (int d = 1; d < 64; d <<= 1) {
    int o = __shfl_up(inc, d, 64);
    if (lane >= d) inc += o;
  }
  if (lane == 63) wsum[wv] = inc;
  __syncthreads();
  int wpre = 0;
  for (int w = 0; w < wv; ++w) wpre += wsum[w];
  int exc = wpre + inc - s;
  int run = exc;
#pragma unroll
  for (int j = 0; j < 4; ++j) {
    if (base + j < NKEY) offs[base + j] = run;
    run += v[j];
  }
  if (t == 255) blockSums[b] = wpre + inc;
}

__global__ void scan2(const int* __restrict__ blockSums, int* __restrict__ blockOff,
                      int nb, int* __restrict__ offs_last) {
  if (threadIdx.x == 0 && blockIdx.x == 0) {
    int run = 0;
    for (int i = 0; i < nb; ++i) { int c = blockSums[i]; blockOff[i] = run; run += c; }
    *offs_last = run;
  }
}

__global__ __launch_bounds__(256) void scan3(int* __restrict__ offs,
                                             const int* __restrict__ blockOff) {
  int t = threadIdx.x, b = blockIdx.x;
  int add = blockOff[b];
  int base = b * 1024 + t * 4;
#pragma unroll
  for (int j = 0; j < 4; ++j)
    if (base + j < NKEY) offs[base + j] += add;
}

__global__ void scatter_edges(const int* __restrict__ src, const int* __restrict__ dst,
                              const int* __restrict__ typ, const float* __restrict__ w,
                              const int* __restrict__ offs, int* __restrict__ tmpc,
                              int* __restrict__ sortedSrc, float* __restrict__ sortedW) {
  int e = blockIdx.x * blockDim.x + threadIdx.x;
  if (e >= NEDGE) return;
  int key = dst[e] * RNUM + typ[e];
  int pos = offs[key] + atomicAdd(&tmpc[key], 1);
  sortedSrc[pos] = src[e];
  sortedW[pos] = w[e];
}

// convert the 4 stacked fp32 inputs to one bf16 [40000][128]
__global__ void cvt_x(const float* __restrict__ xe, const float* __restrict__ xf,
                      const float* __restrict__ xp, const float* __restrict__ xi,
                      u16* __restrict__ xbf) {
  int i = blockIdx.x * blockDim.x + threadIdx.x;  // one per 4 elems
  if (i >= NNODE * 128 / 4) return;
  int e = i * 4;
  int row = e >> 7, col = e & 127;
  const float* srcp; int lr;
  if (row < 20000)      { srcp = xe; lr = row; }
  else if (row < 30000) { srcp = xf; lr = row - 20000; }
  else if (row < 38000) { srcp = xp; lr = row - 30000; }
  else                  { srcp = xi; lr = row - 38000; }
  f32x4 v = *(const f32x4*)&srcp[(size_t)lr * 128 + col];
  u16x4 o = { f2bf(v[0]), f2bf(v[1]), f2bf(v[2]), f2bf(v[3]) };
  *(u16x4*)&xbf[e] = o;
}

// projWt[t][n][k] = bf16(proj_W[t][k][n])
__global__ void build_projWt(const float* __restrict__ pw, u16* __restrict__ wt) {
  int i = blockIdx.x * blockDim.x + threadIdx.x;
  if (i >= 4 * 256 * 128) return;
  int t = i >> 15, rem = i & 32767, n = rem >> 7, k = rem & 127;
  wt[i] = f2bf(pw[((size_t)t * 128 + k) * 256 + n]);
}

// WallT[l][og][k]: og<1536 -> W_r[k][o] = sum_b comp[l][r][b]*basis[l][b][k][o]
//                  og>=1536 -> root[l][k][og-1536]
__global__ void build_wall(const float* __restrict__ basis, const float* __restrict__ comp,
                           const float* __restrict__ root, u16* __restrict__ wall) {
  int i = blockIdx.x * blockDim.x + threadIdx.x;
  if (i >= 3 * KCAT * 256) return;
  int l = i / (KCAT * 256);
  int rem = i - l * KCAT * 256;
  int og = rem >> 8;
  int k = rem & 255;
  float s;
  if (og < 1536) {
    int r = og >> 8, o = og & 255;
    s = 0.f;
#pragma unroll
    for (int b = 0; b < 8; ++b)
      s += comp[((size_t)l * 6 + r) * 8 + b] *
           basis[(((size_t)l * 8 + b) * 256 + k) * 256 + o];
  } else {
    s = root[((size_t)l * 256 + k) * 256 + (og - 1536)];
  }
  wall[i] = f2bf(s);
}

// Arel[r][c] = ete[r] @ emlp_W[:16, c] + emlp_b[c];  V[c] = emlp_W[16][c]
__global__ void build_arel(const float* __restrict__ ete, const float* __restrict__ emlpW,
                           const float* __restrict__ emlpb, float* __restrict__ Arel,
                           float* __restrict__ V) {
  int i = blockIdx.x * blockDim.x + threadIdx.x;
  if (i < 6 * 256) {
    int r = i >> 8, c = i & 255;
    float s = emlpb[c];
#pragma unroll
    for (int k = 0; k < 16; ++k) s += ete[r * 16 + k] * emlpW[k * 256 + c];
    Arel[i] = s;
  } else if (i < 6 * 256 + 256) {
    V[i - 6 * 256] = emlpW[16 * 256 + (i - 6 * 256)];
  }
}

// ---------------- GEMM: C[M,N] = A[M,K](bf16,row-major) x Bt[N,K](bf16) ----------------
// 128x128 tile, BK=32, 4 waves (2x2 of 64x64), global_load_lds staging (m97 structure)
// XCD_REMAP: 1D grid of 8*chunk*NT blocks; xcd = bid%8 owns a contiguous m-tile chunk,
// n varies fastest within the chunk -> A-panel fetched by exactly one XCD's L2.

template <bool BF16_OUT, bool XCD_REMAP>
__global__ __launch_bounds__(256) void gemm_bf16(const u16* __restrict__ A, int lda,
                                                 const u16* __restrict__ Bt, int ldb,
                                                 void* __restrict__ Cv, int ldc,
                                                 int M, int Ndim, int Kdim) {
  __shared__ __align__(16) u16 As[2][128 * 32];
  __shared__ __align__(16) u16 Bs[2][128 * 32];

  int m_tile, n_tile;
  if constexpr (XCD_REMAP) {
    const int NT = Ndim >> 7;
    const int MT = (M + 127) >> 7;
    const int chunk = (MT + 7) >> 3;
    int bid = blockIdx.x;
    int xcd = bid & 7;
    int slot = bid >> 3;
    m_tile = xcd * chunk + slot / NT;
    n_tile = slot - (slot / NT) * NT;
    if (m_tile >= MT) return;
  } else {
    n_tile = blockIdx.x;
    m_tile = blockIdx.y;
  }
  const int n0 = n_tile * 128;
  const int m0 = m_tile * 128;

  const int tid = threadIdx.x;
  const int v = tid >> 6, lane = tid & 63;
  const int wm = (v >> 1) * 64, wn = (v & 1) * 64;

  f32x4 acc[4][4];
#pragma unroll
  for (int i = 0; i < 4; ++i)
#pragma unroll
    for (int j = 0; j < 4; ++j) acc[i][j] = f32x4{0.f, 0.f, 0.f, 0.f};

  const int nk = Kdim >> 5;

  auto stage = [&](int kt, int buf) {
    const int k0 = kt << 5;
#pragma unroll
    for (int it = 0; it < 2; ++it) {
      int c = v * 64 + it * 256 + lane;
      int row = c >> 2, seg = c & 3;
      int ar = m0 + row; if (ar >= M) ar = M - 1;   // clamp (masked on store)
      const u16* ga = A + (size_t)ar * lda + k0 + seg * 8;
      __builtin_amdgcn_global_load_lds(
          (const __attribute__((address_space(1))) void*)ga,
          (__attribute__((address_space(3))) void*)(&As[buf][(v * 64 + it * 256) * 8]),
          16, 0, 0);
      int br = n0 + row;                             // always < N cols
      const u16* gb = Bt + (size_t)br * ldb + k0 + seg * 8;
      __builtin_amdgcn_global_load_lds(
          (const __attribute__((address_space(1))) void*)gb,
          (__attribute__((address_space(3))) void*)(&Bs[buf][(v * 64 + it * 256) * 8]),
          16, 0, 0);
    }
  };

  stage(0, 0);
  for (int kt = 0; kt < nk; ++kt) {
    __syncthreads();                       // stage(kt) complete, prior reads drained
    if (kt + 1 < nk) stage(kt + 1, (kt + 1) & 1);
    const u16* as = &As[kt & 1][0];
    const u16* bs = &Bs[kt & 1][0];
    bf16x8 af[4], bfr[4];
#pragma unroll
    for (int mi = 0; mi < 4; ++mi)
      af[mi] = *(const bf16x8*)&as[(wm + mi * 16 + (lane & 15)) * 32 + (lane >> 4) * 8];
#pragma unroll
    for (int ni = 0; ni < 4; ++ni)
      bfr[ni] = *(const bf16x8*)&bs[(wn + ni * 16 + (lane & 15)) * 32 + (lane >> 4) * 8];
#pragma unroll
    for (int mi = 0; mi < 4; ++mi)
#pragma unroll
      for (int ni = 0; ni < 4; ++ni)
        acc[mi][ni] = __builtin_amdgcn_mfma_f32_16x16x32_bf16(af[mi], bfr[ni],
                                                              acc[mi][ni], 0, 0, 0);
  }

  const int rr = (lane >> 4) * 4;
  const int cc = lane & 15;
#pragma unroll
  for (int mi = 0; mi < 4; ++mi) {
#pragma unroll
    for (int reg = 0; reg < 4; ++reg) {
      int row = m0 + wm + mi * 16 + rr + reg;
      if (row >= M) continue;
#pragma unroll
      for (int ni = 0; ni < 4; ++ni) {
        if constexpr (BF16_OUT) {
          ((u16*)Cv)[(size_t)row * ldc + n0 + wn + ni * 16 + cc] = f2bf(acc[mi][ni][reg]);
        } else {
          ((float*)Cv)[(size_t)row * ldc + n0 + wn + ni * 16 + cc] = acc[mi][ni][reg];
        }
      }
    }
  }
}

// ---------------- per-row LN (proj phase) ----------------

__global__ __launch_bounds__(256) void proj_ln(const float* __restrict__ y,
                                               const float* __restrict__ pb,
                                               const float* __restrict__ pg,
                                               const float* __restrict__ pbeta,
                                               u16* __restrict__ h_bf) {
  int wid = (blockIdx.x * blockDim.x + threadIdx.x) >> 6;
  int lane = threadIdx.x & 63;
  if (wid >= NNODE) return;
  int t = wid < 20000 ? 0 : (wid < 30000 ? 1 : (wid < 38000 ? 2 : 3));
  size_t base = (size_t)wid * HID + lane * 4;
  int pbase = t * HID + lane * 4;
  f32x4 x = *(const f32x4*)&y[base];
  f32x4 bv0 = *(const f32x4*)&pb[pbase];
  x += bv0;
  float s = x[0] + x[1] + x[2] + x[3];
  float s2 = x[0] * x[0] + x[1] * x[1] + x[2] * x[2] + x[3] * x[3];
#pragma unroll
  for (int d = 1; d < 64; d <<= 1) { s += __shfl_xor(s, d, 64); s2 += __shfl_xor(s2, d, 64); }
  float mean = s * (1.f / HID);
  float var = s2 * (1.f / HID) - mean * mean;
  float rs = rsqrtf(var + EPSV);
  f32x4 gv = *(const f32x4*)&pg[pbase];
  f32x4 bv = *(const f32x4*)&pbeta[pbase];
  u16x4 hb;
#pragma unroll
  for (int j = 0; j < 4; ++j) {
    float tv = (x[j] - mean) * rs * gv[j] + bv[j];
    tv = tv > 0.f ? tv : 0.f;
    hb[j] = f2bf(tv);
  }
  *(u16x4*)&h_bf[base] = hb;
}

// ---------------- edge_bias (once) ----------------

__global__ __launch_bounds__(256) void build_edge_bias(const int* __restrict__ offs,
                                                       const float* __restrict__ sortedW,
                                                       const float* __restrict__ Arel,
                                                       const float* __restrict__ V,
                                                       u16* __restrict__ ebias) {
  int n = (blockIdx.x * blockDim.x + threadIdx.x) >> 6;
  int lane = threadIdx.x & 63;
  if (n >= NNODE) return;
  f32x4 vv = *(const f32x4*)&V[lane * 4];
  f32x4 acc = {0.f, 0.f, 0.f, 0.f};
  int beg0 = offs[n * RNUM];
#pragma unroll
  for (int r = 0; r < RNUM; ++r) {
    int b0 = offs[n * RNUM + r], b1 = offs[n * RNUM + r + 1];
    if (b0 == b1) continue;
    f32x4 av = *(const f32x4*)&Arel[r * HID + lane * 4];
    for (int p = b0; p < b1; ++p) {
      float wv = sortedW[p];
#pragma unroll
      for (int j = 0; j < 4; ++j) {
        float t = av[j] + wv * vv[j];
        acc[j] += t > 0.f ? t : 0.f;
      }
    }
  }
  int deg = offs[n * RNUM + RNUM] - beg0;
  float sc = 0.1f / (float)(deg > 1 ? deg : 1);
  u16x4 o = { f2bf(acc[0] * sc), f2bf(acc[1] * sc), f2bf(acc[2] * sc), f2bf(acc[3] * sc) };
  *(u16x4*)&ebias[(size_t)n * HID + lane * 4] = o;
}

// ---------------- fused aggregation + epilogue (per layer) ----------------
// one wave per node. Batched gather: iterate the node's full edge range in
// batches of 4 independent src->z dependent-load chains; relation classified
// per edge via boundary compares (cndmask chain, no runtime-indexed arrays).

__global__ __launch_bounds__(256) void agg_epilogue(const u16* __restrict__ z,
                                                    const int* __restrict__ offs,
                                                    const int* __restrict__ sortedSrc,
                                                    const u16* __restrict__ ebias,
                                                    const float* __restrict__ cb,
                                                    const float* __restrict__ g,
                                                    const float* __restrict__ b,
                                                    u16* __restrict__ h_bf,
                                                    float* __restrict__ outp) {
  int n = (blockIdx.x * blockDim.x + threadIdx.x) >> 6;
  int lane = threadIdx.x & 63;
  if (n >= NNODE) return;
  int col = lane * 4;
  int bo[7];
#pragma unroll
  for (int i = 0; i < 7; ++i) bo[i] = offs[n * RNUM + i];
  float inv0, inv1, inv2, inv3, inv4, inv5;
  {
    int c0 = bo[1]-bo[0], c1 = bo[2]-bo[1], c2 = bo[3]-bo[2];
    int c3 = bo[4]-bo[3], c4 = bo[5]-bo[4], c5 = bo[6]-bo[5];
    inv0 = c0 > 0 ? 1.f / (float)c0 : 0.f;
    inv1 = c1 > 0 ? 1.f / (float)c1 : 0.f;
    inv2 = c2 > 0 ? 1.f / (float)c2 : 0.f;
    inv3 = c3 > 0 ? 1.f / (float)c3 : 0.f;
    inv4 = c4 > 0 ? 1.f / (float)c4 : 0.f;
    inv5 = c5 > 0 ? 1.f / (float)c5 : 0.f;
  }
  f32x4 x = {0.f, 0.f, 0.f, 0.f};
  const int p0 = bo[0], p6 = bo[6];
  for (int p = p0; p < p6; p += 4) {
    int m = p6 - p; if (m > 4) m = 4;
    u16x4 zv[4]; float iv[4];
#pragma unroll
    for (int t = 0; t < 4; ++t) {
      if (t < m) {
        int pe = p + t;
        // classify relation by segment boundaries (uniform across lanes)
        int roff = 0;
        float ivv = inv0;
        if (pe >= bo[1]) { roff = 256;  ivv = inv1; }
        if (pe >= bo[2]) { roff = 512;  ivv = inv2; }
        if (pe >= bo[3]) { roff = 768;  ivv = inv3; }
        if (pe >= bo[4]) { roff = 1024; ivv = inv4; }
        if (pe >= bo[5]) { roff = 1280; ivv = inv5; }
        int src = sortedSrc[pe];
        zv[t] = *(const u16x4*)&z[(size_t)src * KCAT + roff + col];
        iv[t] = ivv;
      }
    }
#pragma unroll
    for (int t = 0; t < 4; ++t) {
      if (t < m) {
#pragma unroll
        for (int j = 0; j < 4; ++j) x[j] += bf2f(zv[t][j]) * iv[t];
      }
    }
  }
  // root part + conv bias + edge bias
  u16x4 zr = *(const u16x4*)&z[(size_t)n * KCAT + 1536 + col];
  u16x4 eb = *(const u16x4*)&ebias[(size_t)n * HID + col];
  f32x4 cbv = *(const f32x4*)&cb[col];
#pragma unroll
  for (int j = 0; j < 4; ++j) x[j] += bf2f(zr[j]) + cbv[j] + bf2f(eb[j]);
  // LayerNorm stats over 256 elems
  float s = x[0] + x[1] + x[2] + x[3];
  float s2 = x[0] * x[0] + x[1] * x[1] + x[2] * x[2] + x[3] * x[3];
#pragma unroll
  for (int d = 1; d < 64; d <<= 1) { s += __shfl_xor(s, d, 64); s2 += __shfl_xor(s2, d, 64); }
  float mean = s * (1.f / HID);
  float var = s2 * (1.f / HID) - mean * mean;
  float rs = rsqrtf(var + EPSV);
  f32x4 gv = *(const f32x4*)&g[col];
  f32x4 bv = *(const f32x4*)&b[col];
  size_t base = (size_t)n * HID + col;
  u16x4 hold = *(const u16x4*)&h_bf[base];
  u16x4 hb; f32x4 r;
#pragma unroll
  for (int j = 0; j < 4; ++j) {
    float tv = (x[j] - mean) * rs * gv[j] + bv[j];
    tv = tv > 0.f ? tv : 0.f;
    r[j] = tv + bf2f(hold[j]);
    hb[j] = f2bf(r[j]);
  }
  *(u16x4*)&h_bf[base] = hb;
  if (outp != nullptr && n < NEVENT) *(f32x4*)&outp[base] = r;
}

// ---------------- launch ----------------

extern "C" void kernel_launch(void* const* d_in, const int* in_sizes, int n_in,
                              void* d_out, int out_size, void* d_ws, size_t ws_size,
                              hipStream_t stream) {
  const float* x_event = (const float*)d_in[0];
  const float* x_file  = (const float*)d_in[1];
  const float* x_proc  = (const float*)d_in[2];
  const float* x_ip    = (const float*)d_in[3];
  const int*   e_src   = (const int*)d_in[4];
  const int*   e_dst   = (const int*)d_in[5];
  const int*   e_typ   = (const int*)d_in[6];
  const float* e_w     = (const float*)d_in[7];
  const float* proj_W  = (const float*)d_in[8];
  const float* proj_b  = (const float*)d_in[9];
  const float* proj_g  = (const float*)d_in[10];
  const float* proj_be = (const float*)d_in[11];
  const float* ete     = (const float*)d_in[12];
  const float* emlpW   = (const float*)d_in[13];
  const float* emlpb   = (const float*)d_in[14];
  const float* basis   = (const float*)d_in[15];
  const float* comp    = (const float*)d_in[16];
  const float* root    = (const float*)d_in[17];
  const float* convb   = (const float*)d_in[18];
  const float* ln_g    = (const float*)d_in[19];
  const float* ln_b    = (const float*)d_in[20];
  float* outp = (float*)d_out;

  char* p = (char*)d_ws;
  auto alloc = [&](size_t bytes) {
    char* r = p; p += (bytes + 255) & ~(size_t)255; return r;
  };
  // total ws usage: ~203 MiB
  u16*   z       = (u16*)  alloc((size_t)NNODE * KCAT * 2);   // 143.4 MB
  u16*   h_bf    = (u16*)  alloc((size_t)NNODE * HID * 2);    // 20.5 MB
  u16*   ebias   = (u16*)  alloc((size_t)NNODE * HID * 2);    // 20.5 MB
  u16*   xbf     = (u16*)  alloc((size_t)NNODE * 128 * 2);    // 10.3 MB
  u16*   projWt  = (u16*)  alloc((size_t)4 * HID * 128 * 2);
  u16*   WallT   = (u16*)  alloc((size_t)3 * KCAT * 256 * 2); // 2.75 MB
  float* Arel    = (float*)alloc(6 * HID * 4);
  float* Vv      = (float*)alloc(HID * 4);
  int*   cnt     = (int*)  alloc(NKEY * 4);
  int*   tmpc    = (int*)  alloc(NKEY * 4);
  int*   offs    = (int*)  alloc((NKEY + 1) * 4);
  int*   bSums   = (int*)  alloc(256 * 4);
  int*   bOff    = (int*)  alloc(256 * 4);
  int*   sSrc    = (int*)  alloc((size_t)NEDGE * 4);
  float* sW      = (float*)alloc((size_t)NEDGE * 4);
  float* y       = (float*)z;   // alias: y (proj output, 41 MB fp32) dead before z written
  (void)in_sizes; (void)n_in; (void)out_size; (void)ws_size;

  const int NB1 = (NKEY + 1023) / 1024;  // 235

  zero_ints<<<(NKEY + 255) / 256, 256, 0, stream>>>(cnt, NKEY);
  zero_ints<<<(NKEY + 255) / 256, 256, 0, stream>>>(tmpc, NKEY);
  count_keys<<<(NEDGE + 255) / 256, 256, 0, stream>>>(e_dst, e_typ, cnt);
  scan1<<<NB1, 256, 0, stream>>>(cnt, offs, bSums);
  scan2<<<1, 1, 0, stream>>>(bSums, bOff, NB1, offs + NKEY);
  scan3<<<NB1, 256, 0, stream>>>(offs, bOff);
  scatter_edges<<<(NEDGE + 255) / 256, 256, 0, stream>>>(e_src, e_dst, e_typ, e_w,
                                                         offs, tmpc, sSrc, sW);

  cvt_x<<<(NNODE * 32 + 255) / 256, 256, 0, stream>>>(x_event, x_file, x_proc, x_ip, xbf);
  build_projWt<<<(4 * 256 * 128 + 255) / 256, 256, 0, stream>>>(proj_W, projWt);
  build_wall<<<(3 * KCAT * 256 + 255) / 256, 256, 0, stream>>>(basis, comp, root, WallT);
  build_arel<<<8, 256, 0, stream>>>(ete, emlpW, emlpb, Arel, Vv);

  // per-type input projection GEMMs (write fp32 y = z alias)
  {
    int offr[5] = {0, 20000, 30000, 38000, 40000};
    for (int t = 0; t < 4; ++t) {
      int M = offr[t + 1] - offr[t];
      dim3 g(2, (M + 127) / 128);
      gemm_bf16<false, false><<<g, 256, 0, stream>>>(xbf + (size_t)offr[t] * 128, 128,
                                                     projWt + (size_t)t * HID * 128, 128,
                                                     y + (size_t)offr[t] * HID, HID,
                                                     M, 256, 128);
    }
  }
  proj_ln<<<(NNODE * 64 + 255) / 256, 256, 0, stream>>>(y, proj_b, proj_g, proj_be, h_bf);
  build_edge_bias<<<(NNODE * 64 + 255) / 256, 256, 0, stream>>>(offs, sW, Arel, Vv, ebias);

  // main-GEMM grid: XCD-remapped 1D; MT=313, NT=14, chunk=40 -> 8*40*14 = 4480
  const int MT = (NNODE + 127) / 128, NT = KCAT / 128;
  const int chunk = (MT + 7) / 8;
  const int nblk = 8 * chunk * NT;
  for (int l = 0; l < 3; ++l) {
    // z[40000, 1792] = h_bf[40000, 256] @ WallT_l^T   (bf16 out)
    gemm_bf16<true, true><<<nblk, 256, 0, stream>>>(h_bf, HID,
                                                    WallT + (size_t)l * KCAT * 256, 256,
                                                    z, KCAT, NNODE, KCAT, 256);
    agg_epilogue<<<(NNODE * 64 + 255) / 256, 256, 0, stream>>>(
        z, offs, sSrc, ebias, convb + l * HID, ln_g + l * HID, ln_b + l * HID,
        h_bf, (l == 2) ? outp : nullptr);
  }
}